// Round 11
// baseline (100.768 us; speedup 1.0000x reference)
//
#include <hip/hip_runtime.h>

// CapsuleConv2d fused, MI355X gfx950. ALL I/O FP32.
// B=2, C_in=128 (G=8 x M=16), 32x32, 3x3 pad 1, O=16, L=16 -> C_out=256.
// k-means (dot) routing 3 iters + squash.
//
// v8: block = (pixel, o-half) -> 4096 blocks. R10 analysis: occupancy was
// double-bound at 3 blocks/CU (unified VGPR+AGPR ~165/wave AND 42 KB LDS);
// fix = halve per-thread state AND work AND keep LDS <= 38 KB -> 4 blocks/CU.
// Phase 1: thread (gh,o,l) computes its g-half of priors (288 pkfma),
//   writes all 72 LDS rows in ONE pass (rows split by gh across threads),
//   ONE barrier. gh forced scalar via readfirstlane -> patch stays s_load.
// Phase 2: thread (o,jh,sc) owns 5 rows x 8 l (j-half): U=20 v2f. Dots use
//   ds_swizzle xor-16 partner-add for the full 16-l sum; softmax/v-updates
//   via dpp_add16 within (o,jh) 16-lane groups. Fully scalarized (R9: any
//   indexed local array -> non-pressure scratch spill).

typedef float v2f __attribute__((ext_vector_type(2)));

#define XT_ELEMS (2 * 32 * 32 * 128)   // 1 MB
#define WT_ELEMS (9 * 256 * 16)        // 576 KB
#define COLS 132                       // LDS row stride (floats), 16B-aligned

#define DPP_ADD(a, ctrl)                                                     \
  a += __int_as_float(__builtin_amdgcn_update_dpp(                           \
          0, __float_as_int(a), ctrl, 0xF, 0xF, true))

__device__ __forceinline__ float dpp_add16(float x) {
    // sum across each aligned 16-lane group, broadcast to all 16 lanes.
    float s = x;
    DPP_ADD(s, 0x128); DPP_ADD(s, 0x124); DPP_ADD(s, 0x122); DPP_ADD(s, 0x121);
    return s;
}

__device__ __forceinline__ float swz16_add(float x) {
    // x + value from lane^16 (bit-mode swizzle: xor=16, and=0x1F)
    int y = __builtin_amdgcn_ds_swizzle(__float_as_int(x), 0x401F);
    return x + __int_as_float(y);
}

__device__ __forceinline__ float frcp(float x) {
    return __builtin_amdgcn_rcpf(x);
}

__device__ __forceinline__ v2f pkfma(v2f a, v2f b, v2f c) {
    return __builtin_elementwise_fma(a, b, c);
}

// ---- prep: blocks [0,64) x-transpose, [64,208) weight transpose ----
// xT[b][h][w][c] = x[b][c][h][w];  Wt[(ij*256+t)*16+m] = W[(t*16+m)*9+ij]
__global__ __launch_bounds__(256)
void prep_kernel(const float* __restrict__ x, const float* __restrict__ W,
                 float* __restrict__ xT, float* __restrict__ Wt) {
    const int blk = blockIdx.x;
    const int tid = threadIdx.x;
    if (blk < 64) {
        __shared__ float xs[128 * 33];
        const int b = blk >> 5, h = blk & 31;
        const float* xb = x + b * (128 * 32 * 32) + h * 32;  // [c*1024 + w]
        #pragma unroll
        for (int k = 0; k < 16; ++k) {
            int idx = k * 256 + tid;
            int c = idx >> 5, w = idx & 31;
            xs[c * 33 + w] = xb[c * 1024 + w];   // coalesced read
        }
        __syncthreads();
        float* xo = xT + (b * 32 + h) * 32 * 128;
        #pragma unroll
        for (int k = 0; k < 16; ++k) {
            int idx = k * 256 + tid;
            int w = idx >> 7, c = idx & 127;
            xo[w * 128 + c] = xs[c * 33 + w];    // coalesced write, cf-free read
        }
    } else {
        int idx = (blk - 64) * 256 + tid;        // 0..36863
        int ij = idx >> 12;
        int r  = idx & 4095;
        int tt = r >> 4;
        int m  = r & 15;
        Wt[idx] = W[(tt * 16 + m) * 9 + ij];
    }
}

// ---- phase-1 macros: one prior (row g*9+ij local to gh-half) ----
#define P1_G(G, IJ, GHC)                                                     \
  { v2f a_ = sp2[((GHC) + (G)) * 8 + 0] * Wm0;                               \
    a_ = pkfma(sp2[((GHC) + (G)) * 8 + 1], Wm1, a_);                         \
    a_ = pkfma(sp2[((GHC) + (G)) * 8 + 2], Wm2, a_);                         \
    a_ = pkfma(sp2[((GHC) + (G)) * 8 + 3], Wm3, a_);                         \
    a_ = pkfma(sp2[((GHC) + (G)) * 8 + 4], Wm4, a_);                         \
    a_ = pkfma(sp2[((GHC) + (G)) * 8 + 5], Wm5, a_);                         \
    a_ = pkfma(sp2[((GHC) + (G)) * 8 + 6], Wm6, a_);                         \
    a_ = pkfma(sp2[((GHC) + (G)) * 8 + 7], Wm7, a_);                         \
    wb[((G) * 9 + (IJ)) * COLS] = a_.x + a_.y; }

#define P1_IJ(IJ, GHC)                                                       \
  { const int di = (IJ) / 3, dj = (IJ) % 3;                                  \
    const int hh = h + di - 1, ww = w + dj - 1;                              \
    if ((unsigned)hh < 32u && (unsigned)ww < 32u) {                          \
        const v2f* sp2 = (const v2f*)(xT + ((bb * 32 + hh) * 32 + ww) * 128);\
        const v2f* wp2 = (const v2f*)(Wt + ((IJ) * 256 + tg) * 16);          \
        v2f Wm0 = wp2[0], Wm1 = wp2[1], Wm2 = wp2[2], Wm3 = wp2[3];          \
        v2f Wm4 = wp2[4], Wm5 = wp2[5], Wm6 = wp2[6], Wm7 = wp2[7];          \
        P1_G(0, IJ, GHC) P1_G(1, IJ, GHC) P1_G(2, IJ, GHC) P1_G(3, IJ, GHC)  \
    } else {                                                                 \
        wb[(0 * 9 + (IJ)) * COLS] = 0.0f;                                    \
        wb[(1 * 9 + (IJ)) * COLS] = 0.0f;                                    \
        wb[(2 * 9 + (IJ)) * COLS] = 0.0f;                                    \
        wb[(3 * 9 + (IJ)) * COLS] = 0.0f;                                    \
    } }

#define P1_PASS(GHC)                                                         \
    P1_IJ(0, GHC) P1_IJ(1, GHC) P1_IJ(2, GHC) P1_IJ(3, GHC) P1_IJ(4, GHC)    \
    P1_IJ(5, GHC) P1_IJ(6, GHC) P1_IJ(7, GHC) P1_IJ(8, GHC)

// ---- phase-2 macros ----
#define LOAD_ROW(K)                                                          \
  { const v2f* r2_ = (const v2f*)(rb + (K) * 16 * COLS);                     \
    U##K##0 = r2_[0]; U##K##1 = r2_[1]; U##K##2 = r2_[2]; U##K##3 = r2_[3]; }

#define DOT_ROW(K)                                                           \
  ({ v2f d_ = U##K##0 * V0;                                                  \
     d_ = pkfma(U##K##1, V1, d_); d_ = pkfma(U##K##2, V2, d_);               \
     d_ = pkfma(U##K##3, V3, d_); swz16_add(d_.x + d_.y); })

#define MEANJ(J)                                                             \
  { v2f s_ = (U0##J + U1##J) + (U2##J + U3##J) + U4##J;                      \
    V##J.x = dpp_add16(s_.x) * (1.0f / 72.0f);                               \
    V##J.y = dpp_add16(s_.y) * (1.0f / 72.0f); }

#define UPDJ(J)                                                              \
  { v2f pv_ = e0v * U0##J;                                                   \
    pv_ = pkfma(e1v, U1##J, pv_); pv_ = pkfma(e2v, U2##J, pv_);              \
    pv_ = pkfma(e3v, U3##J, pv_); pv_ = pkfma(e4v, U4##J, pv_);              \
    V##J.x = dpp_add16(pv_.x) * rs;                                          \
    V##J.y = dpp_add16(pv_.y) * rs; }

// ---- main kernel v8: block = (pixel, o-half) ----
__global__ __launch_bounds__(256, 4)
void capsule_v8(const float* __restrict__ xT, const float* __restrict__ Wt,
                float* __restrict__ out) {
    __shared__ float uTs[72 * COLS];         // 38.0 KB
    const int blk = blockIdx.x;              // 4096
    const int pix = blk >> 1, oh = blk & 1;
    const int bb = pix >> 10, h = (pix >> 5) & 31, w = pix & 31;
    const int tid = threadIdx.x;

    // ================= phase 1: priors -> LDS (one pass) =================
    {
        const int rem = tid & 127;           // o(3b) | l(4b)
        const int gh  = __builtin_amdgcn_readfirstlane(tid >> 7);  // scalar
        const int tg  = oh * 128 + rem;      // global channel for weights
        float* wb = uTs + gh * (36 * COLS) + rem;
        if (gh == 0) { P1_PASS(0) } else { P1_PASS(4) }
    }
    __syncthreads();

    // ================= phase 2: routing =================
    const int o2 = tid >> 5;                 // 0..7 (local o)
    const int s  = tid & 31;
    const int jh = s >> 4;                   // l-half
    const int sc = s & 15;                   // row class
    const bool has5 = (sc < 8);
    const float* rb = uTs + sc * COLS + o2 * 16 + jh * 8;

    v2f U00, U01, U02, U03;
    v2f U10, U11, U12, U13;
    v2f U20, U21, U22, U23;
    v2f U30, U31, U32, U33;
    v2f U40, U41, U42, U43;
    U40 = U41 = U42 = U43 = (v2f){0.0f, 0.0f};
    LOAD_ROW(0) LOAD_ROW(1) LOAD_ROW(2) LOAD_ROW(3)
    if (has5) LOAD_ROW(4)

    // init v = mean over n
    v2f V0, V1, V2, V3;
    MEANJ(0) MEANJ(1) MEANJ(2) MEANJ(3)

    // 3 routing iterations
    #pragma unroll 1
    for (int it = 0; it < 3; ++it) {
        v2f ssv = V0 * V0;
        ssv = pkfma(V1, V1, ssv); ssv = pkfma(V2, V2, ssv);
        ssv = pkfma(V3, V3, ssv);
        float ss = swz16_add(ssv.x + ssv.y);      // full 16-l norm^2
        float inv = frcp(fmaxf(sqrtf(ss), 1e-12f));

        float E0 = __expf(DOT_ROW(0) * inv);
        float E1 = __expf(DOT_ROW(1) * inv);
        float E2 = __expf(DOT_ROW(2) * inv);
        float E3 = __expf(DOT_ROW(3) * inv);
        float E4 = has5 ? __expf(DOT_ROW(4) * inv) : 0.0f;
        float ssum = dpp_add16(((E0 + E1) + (E2 + E3)) + E4);
        float rs = frcp(ssum);

        v2f e0v = {E0, E0}, e1v = {E1, E1}, e2v = {E2, E2};
        v2f e3v = {E3, E3}, e4v = {E4, E4};
        UPDJ(0) UPDJ(1) UPDJ(2) UPDJ(3)
    }

    // squash
    v2f ssv = V0 * V0;
    ssv = pkfma(V1, V1, ssv); ssv = pkfma(V2, V2, ssv);
    ssv = pkfma(V3, V3, ssv);
    float ss = swz16_add(ssv.x + ssv.y);
    float scale = sqrtf(ss) * frcp(1.0f + ss);

    // lane sc<8 writes channel c = oh*128 + o2*16 + jh*8 + sc (select j=sc)
    v2f aa0 = (sc & 4) ? V2 : V0;
    v2f aa1 = (sc & 4) ? V3 : V1;
    v2f bb0 = (sc & 2) ? aa1 : aa0;
    float res = ((sc & 1) ? bb0.y : bb0.x) * scale;
    if (sc < 8) {
        int c = oh * 128 + o2 * 16 + jh * 8 + sc;
        out[((bb * 256 + c) * 32 + h) * 32 + w] = res;
    }
}

// ---- fallback (tiny ws): self-contained ----
__global__ __launch_bounds__(256, 1)
void capsule_fb(const float* __restrict__ x, const float* __restrict__ Wraw,
                float* __restrict__ out) {
    __shared__ float patch[9 * 128];
    const int blk = blockIdx.x;
    const int b = blk >> 10, h = (blk >> 5) & 31, w = blk & 31;
    const int t = threadIdx.x;

    const float* xb = x + b * (128 * 32 * 32);
    for (int idx = t; idx < 1152; idx += 256) {
        int c = idx / 9, ij = idx - c * 9;
        int di = ij / 3, dj = ij - di * 3;
        int hh = h + di - 1, ww = w + dj - 1;
        float v = 0.0f;
        if ((unsigned)hh < 32u && (unsigned)ww < 32u)
            v = xb[(c * 32 + hh) * 32 + ww];
        patch[ij * 128 + c] = v;
    }
    __syncthreads();

    float u[72];
    #pragma unroll
    for (int ij = 0; ij < 9; ++ij) {
        float wr[16];
        #pragma unroll
        for (int m = 0; m < 16; ++m) wr[m] = Wraw[(t * 16 + m) * 9 + ij];
        #pragma unroll
        for (int g = 0; g < 8; ++g) {
            float acc = 0.0f;
            #pragma unroll
            for (int m = 0; m < 16; ++m)
                acc = fmaf(patch[ij * 128 + g * 16 + m], wr[m], acc);
            u[g * 9 + ij] = acc;
        }
    }

    float v = 0.0f;
    #pragma unroll
    for (int n = 0; n < 72; ++n) v += u[n];
    v *= (1.0f / 72.0f);
    #pragma unroll 1
    for (int it = 0; it < 3; ++it) {
        float sg = dpp_add16(v * v);
        float vn = v * frcp(fmaxf(sqrtf(sg), 1e-12f));
        float ssum = 0.0f, vacc = 0.0f;
        #pragma unroll
        for (int n = 0; n < 72; ++n) {
            float p = dpp_add16(u[n] * vn);
            float e = __expf(p);
            ssum += e;
            vacc = fmaf(e, u[n], vacc);
        }
        v = vacc * frcp(ssum);
    }
    float sg = dpp_add16(v * v);
    float res = v * sqrtf(sg) * frcp(1.0f + sg);
    out[((b * 256 + t) * 32 + h) * 32 + w] = res;
}

extern "C" void kernel_launch(void* const* d_in, const int* in_sizes, int n_in,
                              void* d_out, int out_size, void* d_ws, size_t ws_size,
                              hipStream_t stream) {
    const float* x = (const float*)d_in[0];   // [2,128,32,32]
    const float* W = (const float*)d_in[1];   // [16,16,16,3,3]
    float* out = (float*)d_out;               // [2,256,32,32]
    float* xT = (float*)d_ws;
    float* Wt = xT + XT_ELEMS;

    const size_t need = (size_t)(XT_ELEMS + WT_ELEMS) * sizeof(float);
    if (ws_size >= need) {
        prep_kernel<<<208, 256, 0, stream>>>(x, W, xT, Wt);
        capsule_v8<<<4096, 256, 0, stream>>>(xT, Wt, out);
    } else {
        capsule_fb<<<2048, 256, 0, stream>>>(x, W, out);
    }
}

// Round 12
// 79.512 us; speedup vs baseline: 1.2673x; 1.2673x over previous
//
#include <hip/hip_runtime.h>

// CapsuleConv2d fused, MI355X gfx950. ALL I/O FP32.
// B=2, C_in=128 (G=8 x M=16), 32x32, 3x3 pad 1, O=16, L=16 -> C_out=256.
// k-means (dot) routing 3 iters + squash.
//
// v9: priors on the MFMA pipe (MfmaUtil was 0.0 for 6 rounds while VALU did
// 600M MACs). Block = 4 pixels x 32 t-cols (4096 blocks, 256 thr).
// Per ij: C[32=4p*8g x 32t] = A[32 x 16m] @ B[16m x 32t] via
// v_mfma_f32_32x32x16_bf16 with 2-term bf16 split (hiA*hiB+loA*hiB+hiA*loB).
// A frags: per-lane 32B loads from L2-resident xT fp32 + in-reg hi/lo split.
// B frags: prep pre-packs weights in exact fragment layout (coalesced x4).
// C (col=lane&31, row=(reg&3)+8*(reg>>2)+4*(lane>>5)) -> u LDS [4p][72n][32t].
// Phase 2 = v8's scalarized register-local routing per pixel-wave.

typedef float v2f __attribute__((ext_vector_type(2)));
typedef int   i4  __attribute__((ext_vector_type(4)));
typedef short bh8 __attribute__((ext_vector_type(8)));
typedef float f16v __attribute__((ext_vector_type(16)));

#define XT_ELEMS (2 * 32 * 32 * 128)   // 1 MB fp32
#define WBF_ELEMS (9 * 8 * 2 * 64 * 8) // 73728 u16 = 144 KB
#define STR 34                         // u LDS row stride (floats)

#define DPP_ADD(a, ctrl)                                                     \
  a += __int_as_float(__builtin_amdgcn_update_dpp(                           \
          0, __float_as_int(a), ctrl, 0xF, 0xF, true))

__device__ __forceinline__ float dpp_add16(float x) {
    float s = x;
    DPP_ADD(s, 0x128); DPP_ADD(s, 0x124); DPP_ADD(s, 0x122); DPP_ADD(s, 0x121);
    return s;
}

__device__ __forceinline__ float swz16_add(float x) {
    // x + value from lane^16 within each 32-lane group
    int y = __builtin_amdgcn_ds_swizzle(__float_as_int(x), 0x401F);
    return x + __int_as_float(y);
}

__device__ __forceinline__ float frcp(float x) {
    return __builtin_amdgcn_rcpf(x);
}

__device__ __forceinline__ v2f pkfma(v2f a, v2f b, v2f c) {
    return __builtin_elementwise_fma(a, b, c);
}

// ---- prep: [0,64) xT transpose; [64,352) Wbf B-fragment pack ----
// xT[b][h][w][c] = x[b][c][h][w]
// Wbf flat idx = (((ij*8+tt)*2+s)*64 + L)*8 + j  (u16 bf16)
//   value: k=(L>>5)*8+j, c=L&31, t=tt*32+c, wv=W[(t*16+k)*9+ij]
//   s=0: hi=trunc-bf16(wv); s=1: lo=trunc-bf16(wv - hi_as_f32)
__global__ __launch_bounds__(256)
void prep_kernel(const float* __restrict__ x, const float* __restrict__ W,
                 float* __restrict__ xT, unsigned short* __restrict__ Wbf) {
    const int blk = blockIdx.x;
    const int tid = threadIdx.x;
    if (blk < 64) {
        __shared__ float xs[128 * 33];
        const int b = blk >> 5, h = blk & 31;
        const float* xb = x + b * (128 * 32 * 32) + h * 32;
        #pragma unroll
        for (int k = 0; k < 16; ++k) {
            int idx = k * 256 + tid;
            int c = idx >> 5, w = idx & 31;
            xs[c * 33 + w] = xb[c * 1024 + w];
        }
        __syncthreads();
        float* xo = xT + (b * 32 + h) * 32 * 128;
        #pragma unroll
        for (int k = 0; k < 16; ++k) {
            int idx = k * 256 + tid;
            int w = idx >> 7, c = idx & 127;
            xo[w * 128 + c] = xs[c * 33 + w];
        }
    } else {
        int idx = (blk - 64) * 256 + tid;     // 0..73727
        int j  = idx & 7;
        int L  = (idx >> 3) & 63;
        int s  = (idx >> 9) & 1;
        int tt = (idx >> 10) & 7;
        int ij = idx >> 13;
        int k  = (L >> 5) * 8 + j;
        int t  = tt * 32 + (L & 31);
        float wv = W[(t * 16 + k) * 9 + ij];
        unsigned bits = __float_as_uint(wv);
        unsigned hib  = bits & 0xFFFF0000u;
        unsigned short val;
        if (s == 0) val = (unsigned short)(hib >> 16);
        else {
            float lo = wv - __uint_as_float(hib);
            val = (unsigned short)(__float_as_uint(lo) >> 16);
        }
        Wbf[idx] = val;
    }
}

// ---- phase-1 macro: one ij tile -> MFMA -> u LDS ----
// C row r = (reg&3)+8*(reg>>2)+4*half: p=reg>>2 (CT), g=(reg&3)+4*half
// addr = (p*72 + g*9 + IJ)*STR + tl = wroff + STR*((reg>>2)*72+(reg&3)*9+IJ)
#define CWR(REG, IJ)                                                         \
    uLds[wroff + STR * ((((REG) >> 2) * 72) + (((REG) & 3) * 9) + (IJ))] =   \
        acc[(REG)];

#define DO_IJ(IJ)                                                            \
  { const int di = (IJ) / 3, dj = (IJ) % 3;                                  \
    const int hh = h + di - 1;                                               \
    const bool hok = (unsigned)hh < 32u;                                     \
    const int hhc = hok ? hh : 0;                                            \
    const int ww = w0 + pl + dj - 1;                                         \
    const bool ok = hok && ((unsigned)ww < 32u);                             \
    const int wwc = ok ? ww : 0;                                             \
    const float* ap = xT + (((bb * 32 + hhc) * 32 + wwc) * 128               \
                            + gl * 16 + half * 8);                           \
    float f0 = ap[0], f1 = ap[1], f2 = ap[2], f3 = ap[3];                    \
    float f4 = ap[4], f5 = ap[5], f6 = ap[6], f7 = ap[7];                    \
    const float msk = ok ? 1.0f : 0.0f;                                      \
    f0 *= msk; f1 *= msk; f2 *= msk; f3 *= msk;                              \
    f4 *= msk; f5 *= msk; f6 *= msk; f7 *= msk;                              \
    unsigned b0 = __float_as_uint(f0), b1 = __float_as_uint(f1);             \
    unsigned b2 = __float_as_uint(f2), b3 = __float_as_uint(f3);             \
    unsigned b4 = __float_as_uint(f4), b5 = __float_as_uint(f5);             \
    unsigned b6 = __float_as_uint(f6), b7 = __float_as_uint(f7);             \
    i4 hp, lp;                                                               \
    hp.x = (int)((b0 >> 16) | (b1 & 0xFFFF0000u));                           \
    hp.y = (int)((b2 >> 16) | (b3 & 0xFFFF0000u));                           \
    hp.z = (int)((b4 >> 16) | (b5 & 0xFFFF0000u));                           \
    hp.w = (int)((b6 >> 16) | (b7 & 0xFFFF0000u));                           \
    unsigned l0 = __float_as_uint(f0 - __uint_as_float(b0 & 0xFFFF0000u));   \
    unsigned l1 = __float_as_uint(f1 - __uint_as_float(b1 & 0xFFFF0000u));   \
    unsigned l2 = __float_as_uint(f2 - __uint_as_float(b2 & 0xFFFF0000u));   \
    unsigned l3 = __float_as_uint(f3 - __uint_as_float(b3 & 0xFFFF0000u));   \
    unsigned l4 = __float_as_uint(f4 - __uint_as_float(b4 & 0xFFFF0000u));   \
    unsigned l5 = __float_as_uint(f5 - __uint_as_float(b5 & 0xFFFF0000u));   \
    unsigned l6 = __float_as_uint(f6 - __uint_as_float(b6 & 0xFFFF0000u));   \
    unsigned l7 = __float_as_uint(f7 - __uint_as_float(b7 & 0xFFFF0000u));   \
    lp.x = (int)((l0 >> 16) | (l1 & 0xFFFF0000u));                           \
    lp.y = (int)((l2 >> 16) | (l3 & 0xFFFF0000u));                           \
    lp.z = (int)((l4 >> 16) | (l5 & 0xFFFF0000u));                           \
    lp.w = (int)((l6 >> 16) | (l7 & 0xFFFF0000u));                           \
    i4 bhiw = bfr[((IJ) * 8 + tt) * 128 + lane];                             \
    i4 blow = bfr[((IJ) * 8 + tt) * 128 + 64 + lane];                        \
    bh8 aHi = __builtin_bit_cast(bh8, hp);                                   \
    bh8 aLo = __builtin_bit_cast(bh8, lp);                                   \
    bh8 bHi = __builtin_bit_cast(bh8, bhiw);                                 \
    bh8 bLo = __builtin_bit_cast(bh8, blow);                                 \
    f16v acc = {0.f,0.f,0.f,0.f,0.f,0.f,0.f,0.f,                             \
                0.f,0.f,0.f,0.f,0.f,0.f,0.f,0.f};                            \
    acc = __builtin_amdgcn_mfma_f32_32x32x16_bf16(aHi, bLo, acc, 0, 0, 0);   \
    acc = __builtin_amdgcn_mfma_f32_32x32x16_bf16(aLo, bHi, acc, 0, 0, 0);   \
    acc = __builtin_amdgcn_mfma_f32_32x32x16_bf16(aHi, bHi, acc, 0, 0, 0);   \
    CWR(0, IJ)  CWR(1, IJ)  CWR(2, IJ)  CWR(3, IJ)                           \
    CWR(4, IJ)  CWR(5, IJ)  CWR(6, IJ)  CWR(7, IJ)                           \
    CWR(8, IJ)  CWR(9, IJ)  CWR(10, IJ) CWR(11, IJ)                          \
    CWR(12, IJ) CWR(13, IJ) CWR(14, IJ) CWR(15, IJ) }

// ---- phase-2 macros (v8 lineage, 5 rows x 8 l per thread) ----
#define LROW(K)                                                              \
  { const v2f* r2_ = (const v2f*)(rb + (K) * 16 * STR);                      \
    U##K##0 = r2_[0]; U##K##1 = r2_[1]; U##K##2 = r2_[2]; U##K##3 = r2_[3]; }

#define DOTR(K)                                                              \
  ({ v2f d_ = U##K##0 * V0;                                                  \
     d_ = pkfma(U##K##1, V1, d_); d_ = pkfma(U##K##2, V2, d_);               \
     d_ = pkfma(U##K##3, V3, d_); swz16_add(d_.x + d_.y); })

#define MEANJ(J)                                                             \
  { v2f s_ = (U0##J + U1##J) + (U2##J + U3##J) + U4##J;                      \
    V##J.x = dpp_add16(s_.x) * (1.0f / 72.0f);                               \
    V##J.y = dpp_add16(s_.y) * (1.0f / 72.0f); }

#define UPDJ(J)                                                              \
  { v2f pv_ = e0v * U0##J;                                                   \
    pv_ = pkfma(e1v, U1##J, pv_); pv_ = pkfma(e2v, U2##J, pv_);              \
    pv_ = pkfma(e3v, U3##J, pv_); pv_ = pkfma(e4v, U4##J, pv_);              \
    V##J.x = dpp_add16(pv_.x) * rs;                                          \
    V##J.y = dpp_add16(pv_.y) * rs; }

// ---- main kernel v9 ----
__global__ __launch_bounds__(256, 4)
void capsule_v9(const float* __restrict__ xT,
                const unsigned short* __restrict__ Wbf,
                float* __restrict__ out) {
    __shared__ float uLds[4 * 72 * STR];     // 38.25 KB
    const int blk = blockIdx.x;              // 4096
    const int tt = blk & 7;                  // t-tile (32 cols)
    const int q  = blk >> 3;                 // pixel quad
    const int bb = q >> 8;
    const int r  = q & 255;
    const int h  = r >> 3;
    const int w0 = (r & 7) << 2;
    const int tid = threadIdx.x;

    // ---- phase 1: MFMA priors ----
    {
        const int lane = tid & 63;
        const int wv   = tid >> 6;
        const int pl   = (lane & 31) >> 3;   // pixel within quad (A row>>3)
        const int gl   = lane & 7;           // group (A row&7)
        const int half = lane >> 5;          // k-half
        const int tl   = lane & 31;          // C col
        const int wroff = tl + STR * 9 * 4 * half;  // + g-offset 4*half*9*STR
        const i4* bfr = (const i4*)Wbf;
        if (wv == 0)      { DO_IJ(0) DO_IJ(4) DO_IJ(8) }
        else if (wv == 1) { DO_IJ(1) DO_IJ(5) }
        else if (wv == 2) { DO_IJ(2) DO_IJ(6) }
        else              { DO_IJ(3) DO_IJ(7) }
    }
    __syncthreads();

    // ---- phase 2: routing. wave = pixel; (o2, jh, sc) in-wave ----
    const int p  = tid >> 6;
    const int i6 = tid & 63;
    const int o2 = i6 >> 5;
    const int jh = (i6 >> 4) & 1;
    const int sc = i6 & 15;
    const bool has5 = (sc < 8);
    const float* rb = uLds + (p * 72 + sc) * STR + o2 * 16 + jh * 8;

    v2f U00, U01, U02, U03;
    v2f U10, U11, U12, U13;
    v2f U20, U21, U22, U23;
    v2f U30, U31, U32, U33;
    v2f U40, U41, U42, U43;
    U40 = U41 = U42 = U43 = (v2f){0.0f, 0.0f};
    LROW(0) LROW(1) LROW(2) LROW(3)
    if (has5) LROW(4)

    v2f V0, V1, V2, V3;
    MEANJ(0) MEANJ(1) MEANJ(2) MEANJ(3)

    #pragma unroll 1
    for (int it = 0; it < 3; ++it) {
        v2f ssv = V0 * V0;
        ssv = pkfma(V1, V1, ssv); ssv = pkfma(V2, V2, ssv);
        ssv = pkfma(V3, V3, ssv);
        float ss = swz16_add(ssv.x + ssv.y);
        float inv = frcp(fmaxf(sqrtf(ss), 1e-12f));

        float E0 = __expf(DOTR(0) * inv);
        float E1 = __expf(DOTR(1) * inv);
        float E2 = __expf(DOTR(2) * inv);
        float E3 = __expf(DOTR(3) * inv);
        float E4 = has5 ? __expf(DOTR(4) * inv) : 0.0f;
        float ssum = dpp_add16(((E0 + E1) + (E2 + E3)) + E4);
        float rs = frcp(ssum);

        v2f e0v = {E0, E0}, e1v = {E1, E1}, e2v = {E2, E2};
        v2f e3v = {E3, E3}, e4v = {E4, E4};
        UPDJ(0) UPDJ(1) UPDJ(2) UPDJ(3)
    }

    v2f ssv = V0 * V0;
    ssv = pkfma(V1, V1, ssv); ssv = pkfma(V2, V2, ssv);
    ssv = pkfma(V3, V3, ssv);
    float ss = swz16_add(ssv.x + ssv.y);
    float scale = sqrtf(ss) * frcp(1.0f + ss);

    v2f aa0 = (sc & 4) ? V2 : V0;
    v2f aa1 = (sc & 4) ? V3 : V1;
    v2f bb0 = (sc & 2) ? aa1 : aa0;
    float res = ((sc & 1) ? bb0.y : bb0.x) * scale;
    if (sc < 8) {
        int tg = tt * 32 + o2 * 16 + jh * 8 + sc;   // global channel
        out[((bb * 256 + tg) * 32 + h) * 32 + w0 + p] = res;
    }
}

// ---- fallback (tiny ws): self-contained ----
__global__ __launch_bounds__(256, 1)
void capsule_fb(const float* __restrict__ x, const float* __restrict__ Wraw,
                float* __restrict__ out) {
    __shared__ float patch[9 * 128];
    const int blk = blockIdx.x;
    const int b = blk >> 10, h = (blk >> 5) & 31, w = blk & 31;
    const int t = threadIdx.x;

    const float* xb = x + b * (128 * 32 * 32);
    for (int idx = t; idx < 1152; idx += 256) {
        int c = idx / 9, ij = idx - c * 9;
        int di = ij / 3, dj = ij - di * 3;
        int hh = h + di - 1, ww = w + dj - 1;
        float v = 0.0f;
        if ((unsigned)hh < 32u && (unsigned)ww < 32u)
            v = xb[(c * 32 + hh) * 32 + ww];
        patch[ij * 128 + c] = v;
    }
    __syncthreads();

    float u[72];
    #pragma unroll
    for (int ij = 0; ij < 9; ++ij) {
        float wr[16];
        #pragma unroll
        for (int m = 0; m < 16; ++m) wr[m] = Wraw[(t * 16 + m) * 9 + ij];
        #pragma unroll
        for (int g = 0; g < 8; ++g) {
            float acc = 0.0f;
            #pragma unroll
            for (int m = 0; m < 16; ++m)
                acc = fmaf(patch[ij * 128 + g * 16 + m], wr[m], acc);
            u[g * 9 + ij] = acc;
        }
    }

    float v = 0.0f;
    #pragma unroll
    for (int n = 0; n < 72; ++n) v += u[n];
    v *= (1.0f / 72.0f);
    #pragma unroll 1
    for (int it = 0; it < 3; ++it) {
        float sg = dpp_add16(v * v);
        float vn = v * frcp(fmaxf(sqrtf(sg), 1e-12f));
        float ssum = 0.0f, vacc = 0.0f;
        #pragma unroll
        for (int n = 0; n < 72; ++n) {
            float pp = dpp_add16(u[n] * vn);
            float e = __expf(pp);
            ssum += e;
            vacc = fmaf(e, u[n], vacc);
        }
        v = vacc * frcp(ssum);
    }
    float sg = dpp_add16(v * v);
    float res = v * sqrtf(sg) * frcp(1.0f + sg);
    out[((b * 256 + t) * 32 + h) * 32 + w] = res;
}

extern "C" void kernel_launch(void* const* d_in, const int* in_sizes, int n_in,
                              void* d_out, int out_size, void* d_ws, size_t ws_size,
                              hipStream_t stream) {
    const float* x = (const float*)d_in[0];   // [2,128,32,32]
    const float* W = (const float*)d_in[1];   // [16,16,16,3,3]
    float* out = (float*)d_out;               // [2,256,32,32]
    float* xT = (float*)d_ws;
    unsigned short* Wbf = (unsigned short*)(xT + XT_ELEMS);

    const size_t need = (size_t)XT_ELEMS * 4 + (size_t)WBF_ELEMS * 2;
    if (ws_size >= need) {
        prep_kernel<<<352, 256, 0, stream>>>(x, W, xT, Wbf);
        capsule_v9<<<4096, 256, 0, stream>>>(xT, Wbf, out);
    } else {
        capsule_fb<<<2048, 256, 0, stream>>>(x, W, out);
    }
}